// Round 1
// baseline (135.056 us; speedup 1.0000x reference)
//
#include <hip/hip_runtime.h>

#define NB 512
#define NT 256
#define NC 384
#define NH 64

typedef __bf16 bf16x8 __attribute__((ext_vector_type(8)));
typedef float f32x16 __attribute__((ext_vector_type(16)));
typedef unsigned int u32;
typedef unsigned short u16;

__device__ __forceinline__ u16 f2bf(float x) {
  u32 u = __builtin_bit_cast(u32, x);
  u32 r = (u + 0x7fffu + ((u >> 16) & 1u)) >> 16;  // RNE
  return (u16)r;
}
__device__ __forceinline__ u32 pkbf(float lo, float hi) {
  u32 r;
  asm("v_cvt_pk_bf16_f32 %0, %1, %2" : "=v"(r) : "v"(lo), "v"(hi));
  return r;
}

// ---------------- kernel 0: W (3x[64][384] f32) -> combined [192][384] bf16 ----
// rows 0..63 = Wk, 64..127 = Wq, 128..191 = Wv
__global__ __launch_bounds__(256) void wconv_k(const float* __restrict__ wk,
                                               const float* __restrict__ wq,
                                               const float* __restrict__ wv,
                                               u16* __restrict__ wb) {
  int i = blockIdx.x * 256 + threadIdx.x;
  if (i >= 192 * NC) return;
  int row = i / NC, col = i - row * NC;
  const float* s = (row < 64) ? wk : ((row < 128) ? wq : wv);
  wb[i] = f2bf(s[(row & 63) * NC + col]);
}

// ---------------- kernel 1: QKV projection GEMM ------------------------------
// C[m][n] = sum_c x[m][c] * W[n][c];  M=131072, K=384, N=192
// block: 128 rows x 192 cols, 4 waves (each wave 32 rows x 192 cols)
// K chunked by 64, double-buffered LDS, XOR-swizzle byte^=(row&7)<<4
__global__ __launch_bounds__(256) void qkv_gemm(const float* __restrict__ x,
                                                const u16* __restrict__ wb,
                                                u16* __restrict__ kws,
                                                u16* __restrict__ qws,
                                                u16* __restrict__ vws) {
  __shared__ u16 xA[2][128 * 64];  // 32 KB
  __shared__ u16 wB[2][192 * 64];  // 48 KB
  const int tid = threadIdx.x;
  const int m0 = blockIdx.x * 128;
  const int lane = tid & 63, w = tid >> 6;
  const int gl = lane >> 5, l31 = lane & 31;

  float4 xr[8];
  uint4 wr[6];

  auto load_chunk = [&](int kc) {
#pragma unroll
    for (int p = 0; p < 8; ++p) {
      int r = (tid >> 4) + p * 16;
      xr[p] = *(const float4*)(x + (size_t)(m0 + r) * NC + kc * 64 + (tid & 15) * 4);
    }
#pragma unroll
    for (int p = 0; p < 6; ++p) {
      int u = tid + p * 256;
      wr[p] = *(const uint4*)(wb + (u >> 3) * NC + kc * 64 + (u & 7) * 8);
    }
  };
  auto write_chunk = [&](int buf) {
#pragma unroll
    for (int p = 0; p < 8; ++p) {
      int r = (tid >> 4) + p * 16;
      u32 d0 = pkbf(xr[p].x, xr[p].y);
      u32 d1 = pkbf(xr[p].z, xr[p].w);
      int off = r * 128 + (((tid & 15) * 8) ^ ((r & 7) << 4));
      *(uint2*)((char*)&xA[buf][0] + off) = make_uint2(d0, d1);
    }
#pragma unroll
    for (int p = 0; p < 6; ++p) {
      int u = tid + p * 256;
      int row = u >> 3;
      int off = row * 128 + (((u & 7) * 16) ^ ((row & 7) << 4));
      *(uint4*)((char*)&wB[buf][0] + off) = wr[p];
    }
  };

  f32x16 acc[6];
#pragma unroll
  for (int nt = 0; nt < 6; ++nt) {
    f32x16 z = {};
    acc[nt] = z;
  }

  auto compute_chunk = [&](int buf) {
    const char* xb = (const char*)&xA[buf][0];
    const char* wl = (const char*)&wB[buf][0];
    const int arow = w * 32 + l31;
#pragma unroll
    for (int kk = 0; kk < 4; ++kk) {
      int koff = kk * 32 + gl * 16;
      bf16x8 a = *(const bf16x8*)(xb + arow * 128 + (koff ^ ((arow & 7) << 4)));
#pragma unroll
      for (int nt = 0; nt < 6; ++nt) {
        int brow = nt * 32 + l31;
        bf16x8 b = *(const bf16x8*)(wl + brow * 128 + (koff ^ ((brow & 7) << 4)));
        acc[nt] = __builtin_amdgcn_mfma_f32_32x32x16_bf16(a, b, acc[nt], 0, 0, 0);
      }
    }
  };

  load_chunk(0);
  write_chunk(0);
  __syncthreads();
  for (int kc = 0; kc < 6; ++kc) {
    if (kc < 5) load_chunk(kc + 1);       // loads in flight over compute
    compute_chunk(kc & 1);
    if (kc < 5) write_chunk((kc + 1) & 1);  // vmcnt drains here, after compute
    __syncthreads();
  }

  // epilogue: D col = nt*32 + l31 ; D row = (r&3) + 8*(r>>2) + 4*gl (within wave's 32 rows)
#pragma unroll
  for (int nt = 0; nt < 6; ++nt) {
    u16* dst = (nt < 2) ? kws : ((nt < 4) ? qws : vws);
    int col = (nt & 1) * 32 + l31;
#pragma unroll
    for (int r = 0; r < 16; ++r) {
      int m = m0 + w * 32 + (r & 3) + 8 * (r >> 2) + 4 * gl;
      dst[(size_t)m * NH + col] = f2bf(acc[nt][r]);
    }
  }
}

// ---------------- kernel 2: fused causal attention per batch -----------------
// swapped layout: S^T[s][t] = sum_h K[s][h] Q[t][h]; lane owns full row (t = lane&31)
// out^T[h][t] = sum_s V^T[h][s] P^T[s][t]
__global__ __launch_bounds__(256) void attn_k(const u16* __restrict__ kws,
                                              const u16* __restrict__ qws,
                                              const u16* __restrict__ vws,
                                              float* __restrict__ out) {
  __shared__ u16 Klds[256 * 64];      // 32 KB, [s][h], swizzled
  __shared__ u16 VT[64 * 256];        // 32 KB, [h][s], swizzled
  __shared__ u16 Plds[4][32 * 256];   // 64 KB, per-wave [t][s], swizzled
  const int b = blockIdx.x;
  const int tid = threadIdx.x, lane = tid & 63, w = tid >> 6;
  const int gl = lane >> 5, l31 = lane & 31;
  const u16* kb = kws + (size_t)b * NT * NH;
  const u16* qb = qws + (size_t)b * NT * NH;
  const u16* vb = vws + (size_t)b * NT * NH;

  // stage K [256][64] with row-swizzle
#pragma unroll
  for (int p = 0; p < 8; ++p) {
    int u = tid + p * 256;
    int row = u >> 3, c16 = u & 7;
    uint4 d = *(const uint4*)(kb + row * 64 + c16 * 8);
    *(uint4*)((char*)Klds + row * 128 + ((c16 * 16) ^ ((row & 7) << 4))) = d;
  }
  // stage V transposed -> VT [64][256] with row-swizzle
#pragma unroll
  for (int p = 0; p < 8; ++p) {
    int u = tid + p * 256;
    int s = u >> 3, h0 = (u & 7) * 8;
    uint4 d = *(const uint4*)(vb + s * 64 + h0);
    u32 ww[4] = {d.x, d.y, d.z, d.w};
#pragma unroll
    for (int j = 0; j < 4; ++j) {
      int h = h0 + 2 * j;
      *(u16*)((char*)VT + h * 512 + ((s * 2) ^ ((h & 7) << 4))) = (u16)(ww[j] & 0xffffu);
      *(u16*)((char*)VT + (h + 1) * 512 + ((s * 2) ^ (((h + 1) & 7) << 4))) = (u16)(ww[j] >> 16);
    }
  }
  __syncthreads();

  const float cexp = 0.05103103630798287f * 1.4426950408889634f;  // C^-0.5 * log2(e)
  u16* Pw = &Plds[w][0];

#pragma unroll
  for (int pass = 0; pass < 2; ++pass) {
    const int qt = (pass == 0) ? w : 7 - w;  // balanced: w + (7-w)
    const int t0 = qt * 32;

    // Q B-frags: lane holds Q[t = t0+l31][h = kk*16 + gl*8 + j]
    bf16x8 bq[4];
#pragma unroll
    for (int kk = 0; kk < 4; ++kk)
      bq[kk] = *(const bf16x8*)(qb + (t0 + l31) * NH + kk * 16 + gl * 8);

    // S^T = K * Q^T, causal: only frags f <= qt
    f32x16 sf[8];
#pragma unroll
    for (int f = 0; f < 8; ++f) {
      if (f <= qt) {
        f32x16 z = {};
        sf[f] = z;
#pragma unroll
        for (int kk = 0; kk < 4; ++kk) {
          int arow = f * 32 + l31;
          bf16x8 a = *(const bf16x8*)((const char*)Klds + arow * 128 +
                                      ((kk * 32 + gl * 16) ^ ((arow & 7) << 4)));
          sf[f] = __builtin_amdgcn_mfma_f32_32x32x16_bf16(a, bq[kk], sf[f], 0, 0, 0);
        }
      }
    }

    // softmax over s (per lane: t = t0 + l31; s = f*32 + (r&3) + 8*(r>>2) + 4*gl)
    float mmax = -INFINITY;
#pragma unroll
    for (int f = 0; f < 8; ++f) {
      if (f < qt) {
#pragma unroll
        for (int r = 0; r < 16; ++r) mmax = fmaxf(mmax, sf[f][r]);
      } else if (f == qt) {
#pragma unroll
        for (int r = 0; r < 16; ++r) {
          int sloc = (r & 3) + 8 * (r >> 2) + 4 * gl;
          float v = (sloc <= l31) ? sf[f][r] : -INFINITY;
          mmax = fmaxf(mmax, v);
        }
      }
    }
    mmax = fmaxf(mmax, __shfl_xor(mmax, 32));

    float lsum = 0.0f;
#pragma unroll
    for (int f = 0; f < 8; ++f) {
      if (f <= qt) {
#pragma unroll
        for (int r = 0; r < 16; ++r) {
          float e = exp2f((sf[f][r] - mmax) * cexp);
          if (f == qt) {
            int sloc = (r & 3) + 8 * (r >> 2) + 4 * gl;
            e = (sloc <= l31) ? e : 0.0f;
          }
          sf[f][r] = e;
          lsum += e;
        }
      }
    }
    lsum += __shfl_xor(lsum, 32);

    // write P^T (unnormalized, bf16) to per-wave LDS [t=l31][s], swizzled
#pragma unroll
    for (int f = 0; f < 8; ++f) {
      if (f <= qt) {
#pragma unroll
        for (int a4 = 0; a4 < 4; ++a4) {
          u32 d0 = pkbf(sf[f][4 * a4 + 0], sf[f][4 * a4 + 1]);
          u32 d1 = pkbf(sf[f][4 * a4 + 2], sf[f][4 * a4 + 3]);
          int s0 = f * 32 + 8 * a4 + 4 * gl;
          *(uint2*)((char*)Pw + l31 * 512 + ((s0 * 2) ^ ((l31 & 7) << 4))) = make_uint2(d0, d1);
        }
      }
    }

    // PV: out^T[h][t] ; A = VT rows h, B = P^T cols t ; k = s in steps of 16
    f32x16 ao0 = {}, ao1 = {};
    const int nks = (qt + 1) * 2;
#pragma unroll
    for (int ks = 0; ks < 16; ++ks) {
      if (ks < nks) {
        int soff = (ks * 16 + gl * 8) * 2;
        bf16x8 bp = *(const bf16x8*)((char*)Pw + l31 * 512 + (soff ^ ((l31 & 7) << 4)));
        bf16x8 a0 = *(const bf16x8*)((char*)VT + l31 * 512 + (soff ^ ((l31 & 7) << 4)));
        bf16x8 a1 = *(const bf16x8*)((char*)VT + (32 + l31) * 512 + (soff ^ ((l31 & 7) << 4)));
        ao0 = __builtin_amdgcn_mfma_f32_32x32x16_bf16(a0, bp, ao0, 0, 0, 0);
        ao1 = __builtin_amdgcn_mfma_f32_32x32x16_bf16(a1, bp, ao1, 0, 0, 0);
      }
    }

    // epilogue: D col = t = l31 ; D row = h = (r&3) + 8*(r>>2) + 4*gl (+32 for ao1)
    float rl = 1.0f / lsum;
    float* ob = out + ((size_t)b * NT + t0) * NH;
#pragma unroll
    for (int r = 0; r < 16; ++r) {
      int hrow = (r & 3) + 8 * (r >> 2) + 4 * gl;
      ob[(size_t)l31 * NH + hrow] = ao0[r] * rl;
      ob[(size_t)l31 * NH + 32 + hrow] = ao1[r] * rl;
    }
  }
}

// ---------------- launch -----------------------------------------------------
extern "C" void kernel_launch(void* const* d_in, const int* in_sizes, int n_in,
                              void* d_out, int out_size, void* d_ws, size_t ws_size,
                              hipStream_t stream) {
  const float* x = (const float*)d_in[0];
  const float* wk = (const float*)d_in[1];
  const float* wq = (const float*)d_in[2];
  const float* wv = (const float*)d_in[3];
  float* out = (float*)d_out;

  char* ws = (char*)d_ws;
  u16* wb = (u16*)ws;                                   // 147456 B
  u16* kws = (u16*)(ws + (1 << 20));                    // 16 MB each
  u16* qws = kws + (size_t)NB * NT * NH;
  u16* vws = qws + (size_t)NB * NT * NH;

  wconv_k<<<288, 256, 0, stream>>>(wk, wq, wv, wb);
  qkv_gemm<<<1024, 256, 0, stream>>>(x, wb, kws, qws, vws);
  attn_k<<<512, 256, 0, stream>>>(kws, qws, vws, out);
}

// Round 2
// 130.658 us; speedup vs baseline: 1.0337x; 1.0337x over previous
//
#include <hip/hip_runtime.h>

#define NB 512
#define NT 256
#define NC 384
#define NH 64

typedef __bf16 bf16x8 __attribute__((ext_vector_type(8)));
typedef float f32x16 __attribute__((ext_vector_type(16)));
typedef unsigned int u32;
typedef unsigned int u32x4 __attribute__((ext_vector_type(4)));
typedef unsigned short u16;

__device__ __forceinline__ u16 f2bf(float x) {
  u32 u = __builtin_bit_cast(u32, x);
  u32 r = (u + 0x7fffu + ((u >> 16) & 1u)) >> 16;  // RNE
  return (u16)r;
}
__device__ __forceinline__ u32 pkbf(float lo, float hi) {
  u32 r;
  asm("v_cvt_pk_bf16_f32 %0, %1, %2" : "=v"(r) : "v"(lo), "v"(hi));
  return r;
}
__device__ __forceinline__ void pl32swap(u32& a, u32& b) {
  asm volatile("v_permlane32_swap_b32 %0, %1" : "+v"(a), "+v"(b));
}

// ---------------- kernel 0: W (3x[64][384] f32) -> combined [192][384] bf16 ----
// rows 0..63 = Wk, 64..127 = Wq, 128..191 = Wv
__global__ __launch_bounds__(256) void wconv_k(const float* __restrict__ wk,
                                               const float* __restrict__ wq,
                                               const float* __restrict__ wv,
                                               u16* __restrict__ wb) {
  int i = blockIdx.x * 256 + threadIdx.x;
  if (i >= 192 * NC) return;
  int row = i / NC, col = i - row * NC;
  const float* s = (row < 64) ? wk : ((row < 128) ? wq : wv);
  wb[i] = f2bf(s[(row & 63) * NC + col]);
}

// ---------------- kernel 1: QKV projection GEMM ------------------------------
// C[m][n] = sum_c x[m][c] * W[n][c];  M=131072, K=384, N=192
// block: 128 rows x 192 cols, 4 waves (each wave 32 rows x 192 cols)
// K chunked by 64, double-buffered LDS, XOR-swizzle byte^=(row&7)<<4
__global__ __launch_bounds__(256) void qkv_gemm(const float* __restrict__ x,
                                                const u16* __restrict__ wb,
                                                u16* __restrict__ kws,
                                                u16* __restrict__ qws,
                                                u16* __restrict__ vws) {
  __shared__ u16 xA[2][128 * 64];  // 32 KB
  __shared__ u16 wB[2][192 * 64];  // 48 KB
  const int tid = threadIdx.x;
  const int m0 = blockIdx.x * 128;
  const int lane = tid & 63, w = tid >> 6;
  const int gl = lane >> 5, l31 = lane & 31;

  float4 xr[8];
  uint4 wr[6];

  auto load_chunk = [&](int kc) {
#pragma unroll
    for (int p = 0; p < 8; ++p) {
      int r = (tid >> 4) + p * 16;
      xr[p] = *(const float4*)(x + (size_t)(m0 + r) * NC + kc * 64 + (tid & 15) * 4);
    }
#pragma unroll
    for (int p = 0; p < 6; ++p) {
      int u = tid + p * 256;
      wr[p] = *(const uint4*)(wb + (u >> 3) * NC + kc * 64 + (u & 7) * 8);
    }
  };
  auto write_chunk = [&](int buf) {
#pragma unroll
    for (int p = 0; p < 8; ++p) {
      int r = (tid >> 4) + p * 16;
      u32 d0 = pkbf(xr[p].x, xr[p].y);
      u32 d1 = pkbf(xr[p].z, xr[p].w);
      int off = r * 128 + (((tid & 15) * 8) ^ ((r & 7) << 4));
      *(uint2*)((char*)&xA[buf][0] + off) = make_uint2(d0, d1);
    }
#pragma unroll
    for (int p = 0; p < 6; ++p) {
      int u = tid + p * 256;
      int row = u >> 3;
      int off = row * 128 + (((u & 7) * 16) ^ ((row & 7) << 4));
      *(uint4*)((char*)&wB[buf][0] + off) = wr[p];
    }
  };

  f32x16 acc[6];
#pragma unroll
  for (int nt = 0; nt < 6; ++nt) {
    f32x16 z = {};
    acc[nt] = z;
  }

  auto compute_chunk = [&](int buf) {
    const char* xb = (const char*)&xA[buf][0];
    const char* wl = (const char*)&wB[buf][0];
    const int arow = w * 32 + l31;
#pragma unroll
    for (int kk = 0; kk < 4; ++kk) {
      int koff = kk * 32 + gl * 16;
      bf16x8 a = *(const bf16x8*)(xb + arow * 128 + (koff ^ ((arow & 7) << 4)));
#pragma unroll
      for (int nt = 0; nt < 6; ++nt) {
        int brow = nt * 32 + l31;
        bf16x8 b = *(const bf16x8*)(wl + brow * 128 + (koff ^ ((brow & 7) << 4)));
        acc[nt] = __builtin_amdgcn_mfma_f32_32x32x16_bf16(a, b, acc[nt], 0, 0, 0);
      }
    }
  };

  load_chunk(0);
  write_chunk(0);
  __syncthreads();
  for (int kc = 0; kc < 6; ++kc) {
    if (kc < 5) load_chunk(kc + 1);       // loads in flight over compute
    compute_chunk(kc & 1);
    if (kc < 5) write_chunk((kc + 1) & 1);  // vmcnt drains here, after compute
    __syncthreads();
  }

  // epilogue: D col = nt*32 + l31 ; D row = (r&3) + 8*(r>>2) + 4*gl (within wave's 32 rows)
#pragma unroll
  for (int nt = 0; nt < 6; ++nt) {
    u16* dst = (nt < 2) ? kws : ((nt < 4) ? qws : vws);
    int col = (nt & 1) * 32 + l31;
#pragma unroll
    for (int r = 0; r < 16; ++r) {
      int m = m0 + w * 32 + (r & 3) + 8 * (r >> 2) + 4 * gl;
      dst[(size_t)m * NH + col] = f2bf(acc[nt][r]);
    }
  }
}

// ---------------- kernel 2: fused causal attention per batch -----------------
// swapped layout: S^T[s][t] = sum_h K[s][h] Q[t][h]; lane owns full row (t = lane&31)
// P^T -> PV B-frags built fully in-register via cvt_pk + permlane32_swap (T12)
// out^T[h][t] = sum_s V^T[h][s] P^T[s][t]
__global__ __launch_bounds__(256) void attn_k(const u16* __restrict__ kws,
                                              const u16* __restrict__ qws,
                                              const u16* __restrict__ vws,
                                              float* __restrict__ out) {
  __shared__ u16 Klds[256 * 64];      // 32 KB, [s][h], swizzled
  __shared__ u16 VT[64 * 256];        // 32 KB, [h][s], swizzled
  const int b = blockIdx.x;
  const int tid = threadIdx.x, lane = tid & 63, w = tid >> 6;
  const int gl = lane >> 5, l31 = lane & 31;
  const u16* kb = kws + (size_t)b * NT * NH;
  const u16* qb = qws + (size_t)b * NT * NH;
  const u16* vb = vws + (size_t)b * NT * NH;

  // stage K [256][64] with row-swizzle
#pragma unroll
  for (int p = 0; p < 8; ++p) {
    int u = tid + p * 256;
    int row = u >> 3, c16 = u & 7;
    uint4 d = *(const uint4*)(kb + row * 64 + c16 * 8);
    *(uint4*)((char*)Klds + row * 128 + ((c16 * 16) ^ ((row & 7) << 4))) = d;
  }
  // stage V transposed -> VT [64][256] with row-swizzle
#pragma unroll
  for (int p = 0; p < 8; ++p) {
    int u = tid + p * 256;
    int s = u >> 3, h0 = (u & 7) * 8;
    uint4 d = *(const uint4*)(vb + s * 64 + h0);
    u32 ww[4] = {d.x, d.y, d.z, d.w};
#pragma unroll
    for (int j = 0; j < 4; ++j) {
      int h = h0 + 2 * j;
      *(u16*)((char*)VT + h * 512 + ((s * 2) ^ ((h & 7) << 4))) = (u16)(ww[j] & 0xffffu);
      *(u16*)((char*)VT + (h + 1) * 512 + ((s * 2) ^ (((h + 1) & 7) << 4))) = (u16)(ww[j] >> 16);
    }
  }
  __syncthreads();

  const float cexp = 0.05103103630798287f * 1.4426950408889634f;  // C^-0.5 * log2(e)

#pragma unroll
  for (int pass = 0; pass < 2; ++pass) {
    const int qt = (pass == 0) ? w : 7 - w;  // balanced: w + (7-w)
    const int t0 = qt * 32;

    // Q B-frags: lane holds Q[t = t0+l31][h = kk*16 + gl*8 + j]
    bf16x8 bq[4];
#pragma unroll
    for (int kk = 0; kk < 4; ++kk)
      bq[kk] = *(const bf16x8*)(qb + (t0 + l31) * NH + kk * 16 + gl * 8);

    // S^T = K * Q^T, causal: only frags f <= qt
    f32x16 sf[8];
#pragma unroll
    for (int f = 0; f < 8; ++f) {
      if (f <= qt) {
        f32x16 z = {};
        sf[f] = z;
#pragma unroll
        for (int kk = 0; kk < 4; ++kk) {
          int arow = f * 32 + l31;
          bf16x8 a = *(const bf16x8*)((const char*)Klds + arow * 128 +
                                      ((kk * 32 + gl * 16) ^ ((arow & 7) << 4)));
          sf[f] = __builtin_amdgcn_mfma_f32_32x32x16_bf16(a, bq[kk], sf[f], 0, 0, 0);
        }
      }
    }

    // softmax over s (per lane: t = t0 + l31; s = f*32 + (r&3) + 8*(r>>2) + 4*gl)
    float mmax = -INFINITY;
#pragma unroll
    for (int f = 0; f < 8; ++f) {
      if (f < qt) {
#pragma unroll
        for (int r = 0; r < 16; ++r) mmax = fmaxf(mmax, sf[f][r]);
      } else if (f == qt) {
#pragma unroll
        for (int r = 0; r < 16; ++r) {
          int sloc = (r & 3) + 8 * (r >> 2) + 4 * gl;
          float v = (sloc <= l31) ? sf[f][r] : -INFINITY;
          mmax = fmaxf(mmax, v);
        }
      }
    }
    mmax = fmaxf(mmax, __shfl_xor(mmax, 32));

    float lsum = 0.0f;
#pragma unroll
    for (int f = 0; f < 8; ++f) {
      if (f <= qt) {
#pragma unroll
        for (int r = 0; r < 16; ++r) {
          float e = exp2f((sf[f][r] - mmax) * cexp);
          if (f == qt) {
            int sloc = (r & 3) + 8 * (r >> 2) + 4 * gl;
            e = (sloc <= l31) ? e : 0.0f;
          }
          sf[f][r] = e;
          lsum += e;
        }
      }
    }
    lsum += __shfl_xor(lsum, 32);

    // PV: out^T[h][t]; A = VT rows h; B-frags built in-register from sf via
    // cvt_pk + permlane32_swap. Lane pair (gl=0, gl=1) at same l31 jointly owns
    // P^T[:, t0+l31]; one swap yields both the even-frag lo/hi dword pairs.
    f32x16 ao0 = {}, ao1 = {};
#pragma unroll
    for (int f = 0; f < 8; ++f) {
      if (f <= qt) {
        u32 a0 = pkbf(sf[f][0], sf[f][1]);
        u32 a1 = pkbf(sf[f][2], sf[f][3]);
        u32 b0 = pkbf(sf[f][4], sf[f][5]);
        u32 b1 = pkbf(sf[f][6], sf[f][7]);
        pl32swap(a0, b0);
        pl32swap(a1, b1);
        u32x4 te = {a0, a1, b0, b1};
        bf16x8 bpe = __builtin_bit_cast(bf16x8, te);
        u32 c0 = pkbf(sf[f][8], sf[f][9]);
        u32 c1 = pkbf(sf[f][10], sf[f][11]);
        u32 d0 = pkbf(sf[f][12], sf[f][13]);
        u32 d1 = pkbf(sf[f][14], sf[f][15]);
        pl32swap(c0, d0);
        pl32swap(c1, d1);
        u32x4 to = {c0, c1, d0, d1};
        bf16x8 bpo = __builtin_bit_cast(bf16x8, to);

        int se = (f * 32 + gl * 8) * 2;        // ks = 2f byte offset
        int so = se + 32;                      // ks = 2f+1
        bf16x8 av0e = *(const bf16x8*)((char*)VT + l31 * 512 + (se ^ ((l31 & 7) << 4)));
        bf16x8 av1e = *(const bf16x8*)((char*)VT + (32 + l31) * 512 + (se ^ ((l31 & 7) << 4)));
        ao0 = __builtin_amdgcn_mfma_f32_32x32x16_bf16(av0e, bpe, ao0, 0, 0, 0);
        ao1 = __builtin_amdgcn_mfma_f32_32x32x16_bf16(av1e, bpe, ao1, 0, 0, 0);
        bf16x8 av0o = *(const bf16x8*)((char*)VT + l31 * 512 + (so ^ ((l31 & 7) << 4)));
        bf16x8 av1o = *(const bf16x8*)((char*)VT + (32 + l31) * 512 + (so ^ ((l31 & 7) << 4)));
        ao0 = __builtin_amdgcn_mfma_f32_32x32x16_bf16(av0o, bpo, ao0, 0, 0, 0);
        ao1 = __builtin_amdgcn_mfma_f32_32x32x16_bf16(av1o, bpo, ao1, 0, 0, 0);
      }
    }

    // epilogue: D col = t = l31 ; D row = h = (r&3) + 8*(r>>2) + 4*gl (+32 for ao1)
    float rl = 1.0f / lsum;
    float* ob = out + ((size_t)b * NT + t0) * NH;
#pragma unroll
    for (int r = 0; r < 16; ++r) {
      int hrow = (r & 3) + 8 * (r >> 2) + 4 * gl;
      ob[(size_t)l31 * NH + hrow] = ao0[r] * rl;
      ob[(size_t)l31 * NH + 32 + hrow] = ao1[r] * rl;
    }
  }
}

// ---------------- launch -----------------------------------------------------
extern "C" void kernel_launch(void* const* d_in, const int* in_sizes, int n_in,
                              void* d_out, int out_size, void* d_ws, size_t ws_size,
                              hipStream_t stream) {
  const float* x = (const float*)d_in[0];
  const float* wk = (const float*)d_in[1];
  const float* wq = (const float*)d_in[2];
  const float* wv = (const float*)d_in[3];
  float* out = (float*)d_out;

  char* ws = (char*)d_ws;
  u16* wb = (u16*)ws;                                   // 147456 B
  u16* kws = (u16*)(ws + (1 << 20));                    // 16 MB each
  u16* qws = kws + (size_t)NB * NT * NH;
  u16* vws = qws + (size_t)NB * NT * NH;

  wconv_k<<<288, 256, 0, stream>>>(wk, wq, wv, wb);
  qkv_gemm<<<1024, 256, 0, stream>>>(x, wb, kws, qws, vws);
  attn_k<<<512, 256, 0, stream>>>(kws, qws, vws, out);
}

// Round 3
// 128.554 us; speedup vs baseline: 1.0506x; 1.0164x over previous
//
#include <hip/hip_runtime.h>

#define NB 512
#define NT 256
#define NC 384
#define NH 64

typedef __bf16 bf16x8 __attribute__((ext_vector_type(8)));
typedef float f32x16 __attribute__((ext_vector_type(16)));
typedef unsigned int u32;
typedef unsigned int u32x4 __attribute__((ext_vector_type(4)));
typedef unsigned short u16;

__device__ __forceinline__ u16 f2bf(float x) {
  u32 u = __builtin_bit_cast(u32, x);
  u32 r = (u + 0x7fffu + ((u >> 16) & 1u)) >> 16;  // RNE
  return (u16)r;
}
__device__ __forceinline__ u32 pkbf(float lo, float hi) {
  u32 r;
  asm("v_cvt_pk_bf16_f32 %0, %1, %2" : "=v"(r) : "v"(lo), "v"(hi));
  return r;
}
__device__ __forceinline__ void pl32swap(u32& a, u32& b) {
  asm volatile("v_permlane32_swap_b32 %0, %1" : "+v"(a), "+v"(b));
}

// ---------------- kernel 0: W (3x[64][384] f32) -> combined [192][384] bf16 ----
__global__ __launch_bounds__(256) void wconv_k(const float* __restrict__ wk,
                                               const float* __restrict__ wq,
                                               const float* __restrict__ wv,
                                               u16* __restrict__ wb) {
  int i = blockIdx.x * 256 + threadIdx.x;
  if (i >= 192 * NC) return;
  int row = i / NC, col = i - row * NC;
  const float* s = (row < 64) ? wk : ((row < 128) ? wq : wv);
  wb[i] = f2bf(s[(row & 63) * NC + col]);
}

// ---------------- kernel 1: QKV projection GEMM ------------------------------
// C[m][n] = sum_c x[m][c] * W[n][c];  M=131072, K=384, N=192
// block: 128 rows x 192 cols, 4 waves; K chunked by 64, double-buffered LDS.
// Epilogue: acc -> LDS (row-major) -> full-line uint4 global stores.
__global__ __launch_bounds__(256) void qkv_gemm(const float* __restrict__ x,
                                                const u16* __restrict__ wb,
                                                u16* __restrict__ kws,
                                                u16* __restrict__ qws,
                                                u16* __restrict__ vws) {
  __shared__ u16 xA[2][128 * 64];  // 32 KB
  __shared__ u16 wB[2][192 * 64];  // 48 KB (reused as epilogue scratch)
  const int tid = threadIdx.x;
  const int m0 = blockIdx.x * 128;
  const int lane = tid & 63, w = tid >> 6;
  const int gl = lane >> 5, l31 = lane & 31;

  float4 xr[8];
  uint4 wr[6];

  auto load_chunk = [&](int kc) {
#pragma unroll
    for (int p = 0; p < 8; ++p) {
      int r = (tid >> 4) + p * 16;
      xr[p] = *(const float4*)(x + (size_t)(m0 + r) * NC + kc * 64 + (tid & 15) * 4);
    }
#pragma unroll
    for (int p = 0; p < 6; ++p) {
      int u = tid + p * 256;
      wr[p] = *(const uint4*)(wb + (u >> 3) * NC + kc * 64 + (u & 7) * 8);
    }
  };
  auto write_chunk = [&](int buf) {
#pragma unroll
    for (int p = 0; p < 8; ++p) {
      int r = (tid >> 4) + p * 16;
      u32 d0 = pkbf(xr[p].x, xr[p].y);
      u32 d1 = pkbf(xr[p].z, xr[p].w);
      int off = r * 128 + (((tid & 15) * 8) ^ ((r & 7) << 4));
      *(uint2*)((char*)&xA[buf][0] + off) = make_uint2(d0, d1);
    }
#pragma unroll
    for (int p = 0; p < 6; ++p) {
      int u = tid + p * 256;
      int row = u >> 3;
      int off = row * 128 + (((u & 7) * 16) ^ ((row & 7) << 4));
      *(uint4*)((char*)&wB[buf][0] + off) = wr[p];
    }
  };

  f32x16 acc[6];
#pragma unroll
  for (int nt = 0; nt < 6; ++nt) {
    f32x16 z = {};
    acc[nt] = z;
  }

  auto compute_chunk = [&](int buf) {
    const char* xb = (const char*)&xA[buf][0];
    const char* wl = (const char*)&wB[buf][0];
    const int arow = w * 32 + l31;
#pragma unroll
    for (int kk = 0; kk < 4; ++kk) {
      int koff = kk * 32 + gl * 16;
      bf16x8 a = *(const bf16x8*)(xb + arow * 128 + (koff ^ ((arow & 7) << 4)));
#pragma unroll
      for (int nt = 0; nt < 6; ++nt) {
        int brow = nt * 32 + l31;
        bf16x8 b = *(const bf16x8*)(wl + brow * 128 + (koff ^ ((brow & 7) << 4)));
        acc[nt] = __builtin_amdgcn_mfma_f32_32x32x16_bf16(a, b, acc[nt], 0, 0, 0);
      }
    }
  };

  load_chunk(0);
  write_chunk(0);
  __syncthreads();
  for (int kc = 0; kc < 6; ++kc) {
    if (kc < 5) load_chunk(kc + 1);
    compute_chunk(kc & 1);
    if (kc < 5) write_chunk((kc + 1) & 1);
    __syncthreads();
  }

  // ---- epilogue: bounce through LDS for full-line coalesced stores ----
  u16* Cs = &wB[0][0];  // 48 KB == 3 * 128 * 64 * 2B exactly
#pragma unroll
  for (int nt = 0; nt < 6; ++nt) {
    int tens = nt >> 1;
    int col = (nt & 1) * 32 + l31;
#pragma unroll
    for (int r = 0; r < 16; ++r) {
      int mloc = w * 32 + (r & 3) + 8 * (r >> 2) + 4 * gl;
      Cs[(tens * 128 + mloc) * 64 + col] = f2bf(acc[nt][r]);
    }
  }
  __syncthreads();
  {
    u16* const bases[3] = {kws, qws, vws};
    const uint4* src = (const uint4*)Cs;
#pragma unroll
    for (int i = 0; i < 12; ++i) {
      int u = tid + i * 256;            // 0..3071 ; u>>10 uniform per i
      int tens = u >> 10;
      uint4 d = src[u];
      *(uint4*)((char*)(bases[tens] + (size_t)m0 * NH) + (size_t)(u & 1023) * 16) = d;
    }
  }
}

// ---------------- kernel 2: fused causal attention per batch -----------------
// swapped layout: S^T[s][t] = sum_h K[s][h] Q[t][h]; lane owns full row (t = lane&31)
// P^T -> PV B-frags built fully in-register via cvt_pk + permlane32_swap (T12)
__global__ __launch_bounds__(256) void attn_k(const u16* __restrict__ kws,
                                              const u16* __restrict__ qws,
                                              const u16* __restrict__ vws,
                                              float* __restrict__ out) {
  __shared__ u16 Klds[256 * 64];      // 32 KB, [s][h], swizzled
  __shared__ u16 VT[64 * 256];        // 32 KB, [h][s], swizzled
  const int b = blockIdx.x;
  const int tid = threadIdx.x, lane = tid & 63, w = tid >> 6;
  const int gl = lane >> 5, l31 = lane & 31;
  const u16* kb = kws + (size_t)b * NT * NH;
  const u16* qb = qws + (size_t)b * NT * NH;
  const u16* vb = vws + (size_t)b * NT * NH;

#pragma unroll
  for (int p = 0; p < 8; ++p) {
    int u = tid + p * 256;
    int row = u >> 3, c16 = u & 7;
    uint4 d = *(const uint4*)(kb + row * 64 + c16 * 8);
    *(uint4*)((char*)Klds + row * 128 + ((c16 * 16) ^ ((row & 7) << 4))) = d;
  }
#pragma unroll
  for (int p = 0; p < 8; ++p) {
    int u = tid + p * 256;
    int s = u >> 3, h0 = (u & 7) * 8;
    uint4 d = *(const uint4*)(vb + s * 64 + h0);
    u32 ww[4] = {d.x, d.y, d.z, d.w};
#pragma unroll
    for (int j = 0; j < 4; ++j) {
      int h = h0 + 2 * j;
      *(u16*)((char*)VT + h * 512 + ((s * 2) ^ ((h & 7) << 4))) = (u16)(ww[j] & 0xffffu);
      *(u16*)((char*)VT + (h + 1) * 512 + ((s * 2) ^ (((h + 1) & 7) << 4))) = (u16)(ww[j] >> 16);
    }
  }
  __syncthreads();

  const float cexp = 0.05103103630798287f * 1.4426950408889634f;  // C^-0.5 * log2(e)

#pragma unroll
  for (int pass = 0; pass < 2; ++pass) {
    const int qt = (pass == 0) ? w : 7 - w;
    const int t0 = qt * 32;

    bf16x8 bq[4];
#pragma unroll
    for (int kk = 0; kk < 4; ++kk)
      bq[kk] = *(const bf16x8*)(qb + (t0 + l31) * NH + kk * 16 + gl * 8);

    f32x16 sf[8];
#pragma unroll
    for (int f = 0; f < 8; ++f) {
      if (f <= qt) {
        f32x16 z = {};
        sf[f] = z;
#pragma unroll
        for (int kk = 0; kk < 4; ++kk) {
          int arow = f * 32 + l31;
          bf16x8 a = *(const bf16x8*)((const char*)Klds + arow * 128 +
                                      ((kk * 32 + gl * 16) ^ ((arow & 7) << 4)));
          sf[f] = __builtin_amdgcn_mfma_f32_32x32x16_bf16(a, bq[kk], sf[f], 0, 0, 0);
        }
      }
    }

    float mmax = -INFINITY;
#pragma unroll
    for (int f = 0; f < 8; ++f) {
      if (f < qt) {
#pragma unroll
        for (int r = 0; r < 16; ++r) mmax = fmaxf(mmax, sf[f][r]);
      } else if (f == qt) {
#pragma unroll
        for (int r = 0; r < 16; ++r) {
          int sloc = (r & 3) + 8 * (r >> 2) + 4 * gl;
          float v = (sloc <= l31) ? sf[f][r] : -INFINITY;
          mmax = fmaxf(mmax, v);
        }
      }
    }
    mmax = fmaxf(mmax, __shfl_xor(mmax, 32));

    float lsum = 0.0f;
#pragma unroll
    for (int f = 0; f < 8; ++f) {
      if (f <= qt) {
#pragma unroll
        for (int r = 0; r < 16; ++r) {
          float e = exp2f((sf[f][r] - mmax) * cexp);
          if (f == qt) {
            int sloc = (r & 3) + 8 * (r >> 2) + 4 * gl;
            e = (sloc <= l31) ? e : 0.0f;
          }
          sf[f][r] = e;
          lsum += e;
        }
      }
    }
    lsum += __shfl_xor(lsum, 32);

    f32x16 ao0 = {}, ao1 = {};
#pragma unroll
    for (int f = 0; f < 8; ++f) {
      if (f <= qt) {
        u32 a0 = pkbf(sf[f][0], sf[f][1]);
        u32 a1 = pkbf(sf[f][2], sf[f][3]);
        u32 b0 = pkbf(sf[f][4], sf[f][5]);
        u32 b1 = pkbf(sf[f][6], sf[f][7]);
        pl32swap(a0, b0);
        pl32swap(a1, b1);
        u32x4 te = {a0, a1, b0, b1};
        bf16x8 bpe = __builtin_bit_cast(bf16x8, te);
        u32 c0 = pkbf(sf[f][8], sf[f][9]);
        u32 c1 = pkbf(sf[f][10], sf[f][11]);
        u32 d0 = pkbf(sf[f][12], sf[f][13]);
        u32 d1 = pkbf(sf[f][14], sf[f][15]);
        pl32swap(c0, d0);
        pl32swap(c1, d1);
        u32x4 to = {c0, c1, d0, d1};
        bf16x8 bpo = __builtin_bit_cast(bf16x8, to);

        int se = (f * 32 + gl * 8) * 2;
        int so = se + 32;
        bf16x8 av0e = *(const bf16x8*)((char*)VT + l31 * 512 + (se ^ ((l31 & 7) << 4)));
        bf16x8 av1e = *(const bf16x8*)((char*)VT + (32 + l31) * 512 + (se ^ ((l31 & 7) << 4)));
        ao0 = __builtin_amdgcn_mfma_f32_32x32x16_bf16(av0e, bpe, ao0, 0, 0, 0);
        ao1 = __builtin_amdgcn_mfma_f32_32x32x16_bf16(av1e, bpe, ao1, 0, 0, 0);
        bf16x8 av0o = *(const bf16x8*)((char*)VT + l31 * 512 + (so ^ ((l31 & 7) << 4)));
        bf16x8 av1o = *(const bf16x8*)((char*)VT + (32 + l31) * 512 + (so ^ ((l31 & 7) << 4)));
        ao0 = __builtin_amdgcn_mfma_f32_32x32x16_bf16(av0o, bpo, ao0, 0, 0, 0);
        ao1 = __builtin_amdgcn_mfma_f32_32x32x16_bf16(av1o, bpo, ao1, 0, 0, 0);
      }
    }

    // epilogue: lane owns out row t = t0+l31; h-groups of 4 are contiguous -> float4
    float rl = 1.0f / lsum;
    float* ob = out + ((size_t)b * NT + t0 + l31) * NH;
#pragma unroll
    for (int g = 0; g < 4; ++g) {
      // r = 4g+j  ->  h = 8g + 4*gl + j
      float4 v0 = make_float4(ao0[4 * g + 0] * rl, ao0[4 * g + 1] * rl,
                              ao0[4 * g + 2] * rl, ao0[4 * g + 3] * rl);
      float4 v1 = make_float4(ao1[4 * g + 0] * rl, ao1[4 * g + 1] * rl,
                              ao1[4 * g + 2] * rl, ao1[4 * g + 3] * rl);
      *(float4*)(ob + 8 * g + 4 * gl) = v0;
      *(float4*)(ob + 32 + 8 * g + 4 * gl) = v1;
    }
  }
}

// ---------------- launch -----------------------------------------------------
extern "C" void kernel_launch(void* const* d_in, const int* in_sizes, int n_in,
                              void* d_out, int out_size, void* d_ws, size_t ws_size,
                              hipStream_t stream) {
  const float* x = (const float*)d_in[0];
  const float* wk = (const float*)d_in[1];
  const float* wq = (const float*)d_in[2];
  const float* wv = (const float*)d_in[3];
  float* out = (float*)d_out;

  char* ws = (char*)d_ws;
  u16* wb = (u16*)ws;                                   // 147456 B
  u16* kws = (u16*)(ws + (1 << 20));                    // 16 MB each
  u16* qws = kws + (size_t)NB * NT * NH;
  u16* vws = qws + (size_t)NB * NT * NH;

  wconv_k<<<288, 256, 0, stream>>>(wk, wq, wv, wb);
  qkv_gemm<<<1024, 256, 0, stream>>>(x, wb, kws, qws, vws);
  attn_k<<<512, 256, 0, stream>>>(kws, qws, vws, out);
}

// Round 4
// 89.919 us; speedup vs baseline: 1.5020x; 1.4297x over previous
//
#include <hip/hip_runtime.h>

#define NB 512
#define NT 256
#define NC 384
#define NH 64

typedef __bf16 bf16x8 __attribute__((ext_vector_type(8)));
typedef float f32x4 __attribute__((ext_vector_type(4)));
typedef float f32x16 __attribute__((ext_vector_type(16)));
typedef unsigned int u32;
typedef unsigned int u32x4 __attribute__((ext_vector_type(4)));
typedef unsigned short u16;

__device__ __forceinline__ u16 f2bf(float x) {
  u32 u = __builtin_bit_cast(u32, x);
  u32 r = (u + 0x7fffu + ((u >> 16) & 1u)) >> 16;  // RNE
  return (u16)r;
}
__device__ __forceinline__ u32 pkbf(float lo, float hi) {
  u32 r;
  asm("v_cvt_pk_bf16_f32 %0, %1, %2" : "=v"(r) : "v"(lo), "v"(hi));
  return r;
}
__device__ __forceinline__ void pl32swap(u32& a, u32& b) {
  asm volatile("v_permlane32_swap_b32 %0, %1" : "+v"(a), "+v"(b));
}

// ---------------- kernel 0: W (3x[64][384] f32) -> combined [192][384] bf16 ----
__global__ __launch_bounds__(256) void wconv_k(const float* __restrict__ wk,
                                               const float* __restrict__ wq,
                                               const float* __restrict__ wv,
                                               u16* __restrict__ wb) {
  int i = blockIdx.x * 256 + threadIdx.x;
  if (i >= 192 * NC) return;
  int row = i / NC, col = i - row * NC;
  const float* s = (row < 64) ? wk : ((row < 128) ? wq : wv);
  wb[i] = f2bf(s[(row & 63) * NC + col]);
}

// ---------------- kernel 1: QKV projection GEMM (barrier-free K-loop) --------
// C[m][n] = sum_c x[m][c] * W[n][c];  M=131072, K=384, N=192
// 1024 threads = 16 waves; W resident in LDS (147 KB, XOR-swizzled granules);
// x streamed global->regs->A-frags (4-stage prefetch); 16x16x32 MFMA;
// no barriers inside the K-loop. Epilogue bounces via the dead W LDS.
__global__ __launch_bounds__(1024) void qkv_gemm(const float* __restrict__ x,
                                                 const u16* __restrict__ wb,
                                                 u16* __restrict__ kws,
                                                 u16* __restrict__ qws,
                                                 u16* __restrict__ vws) {
  __shared__ u16 Wl[192 * 384];  // 147456 B; row stride 768 B; granule gs = gk ^ (row&7)
  const int tid = threadIdx.x;
  const int lane = tid & 63, w = tid >> 6;
  const int l15 = lane & 15, lg = lane >> 4;
  const size_t m0 = (size_t)blockIdx.x * 256;

  // --- issue x prefetch for kk = 0..3 first (hides under W staging) ---
  const float* xp = x + (m0 + (size_t)(w * 16 + l15)) * NC + lg * 8;
  float4 pX[4], pY[4];
#pragma unroll
  for (int s = 0; s < 4; ++s) {
    pX[s] = *(const float4*)(xp + s * 32);
    pY[s] = *(const float4*)(xp + s * 32 + 4);
  }

  // --- stage W into LDS, swizzled: pos(row, gs) holds source granule gs^(row&7) ---
  {
    int rlow = tid >> 4, sub = tid & 15;
#pragma unroll
    for (int i = 0; i < 9; ++i) {
      int rhi = i / 3, third = i - rhi * 3;
      int row = rhi * 64 + rlow;        // 0..191
      int gs = third * 16 + sub;        // 0..47
      int gk = gs ^ (row & 7);
      uint4 d = *(const uint4*)(wb + row * NC + gk * 8);
      *(uint4*)((char*)Wl + row * 768 + gs * 16) = d;
    }
  }
  __syncthreads();

  f32x4 acc[12];
#pragma unroll
  for (int nt = 0; nt < 12; ++nt) {
    f32x4 z = {};
    acc[nt] = z;
  }

  // --- K-loop: 12 steps of K=32, fully independent per wave ---
#pragma unroll
  for (int kk = 0; kk < 12; ++kk) {
    const int st = kk & 3;
    u32 a0 = pkbf(pX[st].x, pX[st].y);
    u32 a1 = pkbf(pX[st].z, pX[st].w);
    u32 a2 = pkbf(pY[st].x, pY[st].y);
    u32 a3 = pkbf(pY[st].z, pY[st].w);
    u32x4 av = {a0, a1, a2, a3};
    bf16x8 afrag = __builtin_bit_cast(bf16x8, av);
    if (kk < 8) {  // distance-4 prefetch
      pX[st] = *(const float4*)(xp + (kk + 4) * 32);
      pY[st] = *(const float4*)(xp + (kk + 4) * 32 + 4);
    }
#pragma unroll
    for (int nt = 0; nt < 12; ++nt) {
      int brow = nt * 16 + l15;
      bf16x8 b = *(const bf16x8*)((const char*)Wl + brow * 768 +
                                  (((kk * 4 + lg) ^ (brow & 7)) << 4));
      acc[nt] = __builtin_amdgcn_mfma_f32_16x16x32_bf16(afrag, b, acc[nt], 0, 0, 0);
    }
  }

  // --- epilogue: acc -> LDS (row-major [256][192] bf16) -> full-line stores ---
  __syncthreads();  // all waves done reading W
#pragma unroll
  for (int nt = 0; nt < 12; ++nt) {
#pragma unroll
    for (int r = 0; r < 4; ++r) {
      int mloc = w * 16 + lg * 4 + r;  // D row = (lane>>4)*4 + reg
      *((u16*)((char*)Wl + mloc * 384) + nt * 16 + l15) = f2bf(acc[nt][r]);
    }
  }
  __syncthreads();
  {
    u16* const bases[3] = {kws, qws, vws};
#pragma unroll
    for (int t = 0; t < 3; ++t) {
#pragma unroll
      for (int i = 0; i < 2; ++i) {
        int idx = i * 1024 + tid;      // 0..2047
        int row = idx >> 3, c16 = idx & 7;
        uint4 d = *(const uint4*)((const char*)Wl + row * 384 + t * 128 + c16 * 16);
        *(uint4*)(bases[t] + (m0 + row) * NH + c16 * 8) = d;
      }
    }
  }
}

// ---------------- kernel 2: fused causal attention per batch -----------------
// swapped layout: S^T[s][t] = sum_h K[s][h] Q[t][h]; lane owns full row (t = lane&31)
// P^T -> PV B-frags built fully in-register via cvt_pk + permlane32_swap (T12)
__global__ __launch_bounds__(256) void attn_k(const u16* __restrict__ kws,
                                              const u16* __restrict__ qws,
                                              const u16* __restrict__ vws,
                                              float* __restrict__ out) {
  __shared__ u16 Klds[256 * 64];      // 32 KB, [s][h], swizzled
  __shared__ u16 VT[64 * 256];        // 32 KB, [h][s], swizzled
  const int b = blockIdx.x;
  const int tid = threadIdx.x, lane = tid & 63, w = tid >> 6;
  const int gl = lane >> 5, l31 = lane & 31;
  const u16* kb = kws + (size_t)b * NT * NH;
  const u16* qb = qws + (size_t)b * NT * NH;
  const u16* vb = vws + (size_t)b * NT * NH;

#pragma unroll
  for (int p = 0; p < 8; ++p) {
    int u = tid + p * 256;
    int row = u >> 3, c16 = u & 7;
    uint4 d = *(const uint4*)(kb + row * 64 + c16 * 8);
    *(uint4*)((char*)Klds + row * 128 + ((c16 * 16) ^ ((row & 7) << 4))) = d;
  }
#pragma unroll
  for (int p = 0; p < 8; ++p) {
    int u = tid + p * 256;
    int s = u >> 3, h0 = (u & 7) * 8;
    uint4 d = *(const uint4*)(vb + s * 64 + h0);
    u32 ww[4] = {d.x, d.y, d.z, d.w};
#pragma unroll
    for (int j = 0; j < 4; ++j) {
      int h = h0 + 2 * j;
      *(u16*)((char*)VT + h * 512 + ((s * 2) ^ ((h & 7) << 4))) = (u16)(ww[j] & 0xffffu);
      *(u16*)((char*)VT + (h + 1) * 512 + ((s * 2) ^ (((h + 1) & 7) << 4))) = (u16)(ww[j] >> 16);
    }
  }
  __syncthreads();

  const float cexp = 0.05103103630798287f * 1.4426950408889634f;  // C^-0.5 * log2(e)

#pragma unroll
  for (int pass = 0; pass < 2; ++pass) {
    const int qt = (pass == 0) ? w : 7 - w;
    const int t0 = qt * 32;

    bf16x8 bq[4];
#pragma unroll
    for (int kk = 0; kk < 4; ++kk)
      bq[kk] = *(const bf16x8*)(qb + (t0 + l31) * NH + kk * 16 + gl * 8);

    f32x16 sf[8];
#pragma unroll
    for (int f = 0; f < 8; ++f) {
      if (f <= qt) {
        f32x16 z = {};
        sf[f] = z;
#pragma unroll
        for (int kk = 0; kk < 4; ++kk) {
          int arow = f * 32 + l31;
          bf16x8 a = *(const bf16x8*)((const char*)Klds + arow * 128 +
                                      ((kk * 32 + gl * 16) ^ ((arow & 7) << 4)));
          sf[f] = __builtin_amdgcn_mfma_f32_32x32x16_bf16(a, bq[kk], sf[f], 0, 0, 0);
        }
      }
    }

    float mmax = -INFINITY;
#pragma unroll
    for (int f = 0; f < 8; ++f) {
      if (f < qt) {
#pragma unroll
        for (int r = 0; r < 16; ++r) mmax = fmaxf(mmax, sf[f][r]);
      } else if (f == qt) {
#pragma unroll
        for (int r = 0; r < 16; ++r) {
          int sloc = (r & 3) + 8 * (r >> 2) + 4 * gl;
          float v = (sloc <= l31) ? sf[f][r] : -INFINITY;
          mmax = fmaxf(mmax, v);
        }
      }
    }
    mmax = fmaxf(mmax, __shfl_xor(mmax, 32));

    float lsum = 0.0f;
#pragma unroll
    for (int f = 0; f < 8; ++f) {
      if (f <= qt) {
#pragma unroll
        for (int r = 0; r < 16; ++r) {
          float e = exp2f((sf[f][r] - mmax) * cexp);
          if (f == qt) {
            int sloc = (r & 3) + 8 * (r >> 2) + 4 * gl;
            e = (sloc <= l31) ? e : 0.0f;
          }
          sf[f][r] = e;
          lsum += e;
        }
      }
    }
    lsum += __shfl_xor(lsum, 32);

    f32x16 ao0 = {}, ao1 = {};
#pragma unroll
    for (int f = 0; f < 8; ++f) {
      if (f <= qt) {
        u32 a0 = pkbf(sf[f][0], sf[f][1]);
        u32 a1 = pkbf(sf[f][2], sf[f][3]);
        u32 b0 = pkbf(sf[f][4], sf[f][5]);
        u32 b1 = pkbf(sf[f][6], sf[f][7]);
        pl32swap(a0, b0);
        pl32swap(a1, b1);
        u32x4 te = {a0, a1, b0, b1};
        bf16x8 bpe = __builtin_bit_cast(bf16x8, te);
        u32 c0 = pkbf(sf[f][8], sf[f][9]);
        u32 c1 = pkbf(sf[f][10], sf[f][11]);
        u32 d0 = pkbf(sf[f][12], sf[f][13]);
        u32 d1 = pkbf(sf[f][14], sf[f][15]);
        pl32swap(c0, d0);
        pl32swap(c1, d1);
        u32x4 to = {c0, c1, d0, d1};
        bf16x8 bpo = __builtin_bit_cast(bf16x8, to);

        int se = (f * 32 + gl * 8) * 2;
        int so = se + 32;
        bf16x8 av0e = *(const bf16x8*)((char*)VT + l31 * 512 + (se ^ ((l31 & 7) << 4)));
        bf16x8 av1e = *(const bf16x8*)((char*)VT + (32 + l31) * 512 + (se ^ ((l31 & 7) << 4)));
        ao0 = __builtin_amdgcn_mfma_f32_32x32x16_bf16(av0e, bpe, ao0, 0, 0, 0);
        ao1 = __builtin_amdgcn_mfma_f32_32x32x16_bf16(av1e, bpe, ao1, 0, 0, 0);
        bf16x8 av0o = *(const bf16x8*)((char*)VT + l31 * 512 + (so ^ ((l31 & 7) << 4)));
        bf16x8 av1o = *(const bf16x8*)((char*)VT + (32 + l31) * 512 + (so ^ ((l31 & 7) << 4)));
        ao0 = __builtin_amdgcn_mfma_f32_32x32x16_bf16(av0o, bpo, ao0, 0, 0, 0);
        ao1 = __builtin_amdgcn_mfma_f32_32x32x16_bf16(av1o, bpo, ao1, 0, 0, 0);
      }
    }

    float rl = 1.0f / lsum;
    float* ob = out + ((size_t)b * NT + t0 + l31) * NH;
#pragma unroll
    for (int g = 0; g < 4; ++g) {
      float4 v0 = make_float4(ao0[4 * g + 0] * rl, ao0[4 * g + 1] * rl,
                              ao0[4 * g + 2] * rl, ao0[4 * g + 3] * rl);
      float4 v1 = make_float4(ao1[4 * g + 0] * rl, ao1[4 * g + 1] * rl,
                              ao1[4 * g + 2] * rl, ao1[4 * g + 3] * rl);
      *(float4*)(ob + 8 * g + 4 * gl) = v0;
      *(float4*)(ob + 32 + 8 * g + 4 * gl) = v1;
    }
  }
}

// ---------------- launch -----------------------------------------------------
extern "C" void kernel_launch(void* const* d_in, const int* in_sizes, int n_in,
                              void* d_out, int out_size, void* d_ws, size_t ws_size,
                              hipStream_t stream) {
  const float* x = (const float*)d_in[0];
  const float* wk = (const float*)d_in[1];
  const float* wq = (const float*)d_in[2];
  const float* wv = (const float*)d_in[3];
  float* out = (float*)d_out;

  char* ws = (char*)d_ws;
  u16* wb = (u16*)ws;                                   // 147456 B
  u16* kws = (u16*)(ws + (1 << 20));                    // 16 MB each
  u16* qws = kws + (size_t)NB * NT * NH;
  u16* vws = qws + (size_t)NB * NT * NH;

  wconv_k<<<288, 256, 0, stream>>>(wk, wq, wv, wb);
  qkv_gemm<<<512, 1024, 0, stream>>>(x, wb, kws, qws, vws);
  attn_k<<<512, 256, 0, stream>>>(kws, qws, vws, out);
}